// Round 8
// baseline (436.749 us; speedup 1.0000x reference)
//
#include <hip/hip_runtime.h>
#include <hip/hip_bf16.h>
#include <math.h>

// Suffix-max scan along H (reverse), NCHW: x[8,128,256,256] f32.
// out[n,c,h,w] = max_{j>=h} x[n,c,j,w].
//
// R8: all-ascending streams ("copy-clone") on the R7 base.
// Evidence: 6 designs (granularity, NT, phasing, dbuf, occupancy) all
// ~115us kernel (~4.4 TB/s) vs 85us copy-rate floor. The ONE untested
// difference vs the 6.3-6.5 TB/s fill/copy kernels: every prior variant
// loaded h DESCENDING (scan fused into load loop). Here loads are
// decoupled: chunk loaded ascending into regs (independent), suffix-max
// done as pure in-register backward pass, stores ascending. Single-
// variable A/B vs R7 (same block shape, occupancy, plain loads/stores).

#define H 256
#define W 256
#define CH 16    // rows per thread
#define NC 16    // chunks per slab (H/CH)

__global__ __launch_bounds__(1024, 8) void VerticalLinePool_kernel(
    const float* __restrict__ x, float* __restrict__ out) {
    const int tid = threadIdx.x;
    const int c  = tid >> 6;             // chunk 0..15 (wave-uniform)
    const int wl = tid & 63;             // column within quarter
    const int q    = blockIdx.x & 3;     // w-quarter
    const int slab = blockIdx.x >> 2;    // (n,c) slab 0..1023

    const size_t col = (size_t)slab * (H * W) + (size_t)q * 64 + wl;
    const float* __restrict__ xp = x + col;
    float* __restrict__ op = out + col;

    const int h0 = c * CH;

    // Phase 1a: ASCENDING independent loads of the chunk into registers.
    float s[CH];
#pragma unroll
    for (int i = 0; i < CH; ++i) {
        s[i] = xp[(size_t)(h0 + i) * W];
    }

    // Phase 1b: in-register suffix-max (no memory ops).
    float run = -INFINITY;
#pragma unroll
    for (int i = CH - 1; i >= 0; --i) {
        run = fmaxf(run, s[i]);
        s[i] = run;
    }

    // Share chunk totals; chunk c needs max over chunks c+1..15.
    __shared__ float tot[NC][64];
    tot[c][wl] = run;
    __syncthreads();

    float M = -INFINITY;                 // loop bounds wave-uniform (c = wave id)
    for (int k = c + 1; k < NC; ++k)
        M = fmaxf(M, tot[k][wl]);

    // Phase 2: ASCENDING stores.
#pragma unroll
    for (int i = 0; i < CH; ++i) {
        op[(size_t)(h0 + i) * W] = fmaxf(s[i], M);
    }
}

extern "C" void kernel_launch(void* const* d_in, const int* in_sizes, int n_in,
                              void* d_out, int out_size, void* d_ws, size_t ws_size,
                              hipStream_t stream) {
    const float* x = (const float*)d_in[0];
    float* out = (float*)d_out;
    const int slabs = in_sizes[0] / (H * W);   // 8*128 = 1024
    VerticalLinePool_kernel<<<slabs * 4, 1024, 0, stream>>>(x, out);
}